// Round 3
// baseline (749.599 us; speedup 1.0000x reference)
//
#include <hip/hip_runtime.h>

#define NROWS 4096
#define NBLK 4
#define DIN 4000
#define DE 128
#define DB 8
#define DLAT 512
#define FANIN 4136
#define KPAD 4224   // 66 * 64
#define NKT 66
#define XC 16000    // NBLK*DIN
#define OUTC 2048   // NBLK*DLAT
#define TC 192      // tail columns: 128 embed + 8 batch + 56 pad

typedef __attribute__((ext_vector_type(8))) short short8;
typedef __attribute__((ext_vector_type(4))) float floatx4;

__device__ __forceinline__ unsigned short f2bf(float f) {
    unsigned int u = __builtin_bit_cast(unsigned int, f);
    u = (u + 0x7FFFu + ((u >> 16) & 1u)) >> 16;
    return (unsigned short)u;
}

__device__ __forceinline__ void async16(const void* g, void* l) {
    __builtin_amdgcn_global_load_lds(
        (const __attribute__((address_space(1))) void*)g,
        (__attribute__((address_space(3))) void*)l, 16, 0, 0);
}

// ---------------------------------------------------------------------------
// Pack W (fp32 [4][4136][512]) -> Wp (bf16 [4][512][4224], n-major, K padded).
// packed k: [0,4000)=x rows, [4000,4032)=0, [4032,4168)=W rows 4000..4135,
// [4168,4224)=0. LDS-transpose tile: both global reads and writes coalesced.
// Grid: 4(b) * 66(kt) * 8(nt) = 2112 blocks x 256.
// ---------------------------------------------------------------------------
__global__ void prep_w(const float* __restrict__ W, unsigned short* __restrict__ Wp) {
    __shared__ unsigned short tile[64 * 68];   // [k 64][n 64], stride 68
    int bid = blockIdx.x;
    int nt = bid & 7;
    int t2 = bid >> 3;
    int kt = t2 % 66;
    int b  = t2 / 66;
    int tid = threadIdx.x;
    int n0 = nt * 64;
    int k0 = kt * 64;
#pragma unroll
    for (int i = 0; i < 4; ++i) {
        int c = i * 256 + tid;
        int r = c >> 4;             // k-row in tile
        int q = (c & 15) * 4;       // n-col
        int pk = k0 + r;
        int wr = (pk < DIN) ? pk : ((pk >= 4032 && pk < 4168) ? pk - 32 : -1);
        float4 v = make_float4(0.f, 0.f, 0.f, 0.f);
        if (wr >= 0)
            v = *reinterpret_cast<const float4*>(W + ((size_t)b * FANIN + wr) * DLAT + n0 + q);
        ushort4 u4 = make_ushort4(f2bf(v.x), f2bf(v.y), f2bf(v.z), f2bf(v.w));
        *reinterpret_cast<ushort4*>(&tile[r * 68 + q]) = u4;
    }
    __syncthreads();
#pragma unroll
    for (int i = 0; i < 2; ++i) {
        int c = i * 256 + tid;
        int nl = c >> 3;            // n within tile
        int kc = c & 7;             // 16B k-chunk
        unsigned short o[8];
#pragma unroll
        for (int j = 0; j < 8; ++j) o[j] = tile[(kc * 8 + j) * 68 + nl];
        *reinterpret_cast<short8*>(Wp + ((size_t)(b * DLAT + n0 + nl)) * KPAD + k0 + kc * 8) =
            *reinterpret_cast<const short8*>(o);
    }
}

// ---------------------------------------------------------------------------
// Pack tail T (bf16 [4096][4][192]): [0,128)=embed_b, [128,136)=batches, rest 0
// ---------------------------------------------------------------------------
__global__ void prep_t(const float* __restrict__ embed, const float* __restrict__ batches,
                       unsigned short* __restrict__ T) {
    int i  = blockIdx.x * 256 + threadIdx.x;   // over 4096*4*192 = 3,145,728
    int t  = i % TC;
    int nb = i / TC;
    int b  = nb & 3;
    int n  = nb >> 2;
    float v = 0.f;
    if (t < DE)            v = embed[(size_t)n * (NBLK * DE) + b * DE + t];
    else if (t < DE + DB)  v = batches[(size_t)n * DB + (t - DE)];
    T[i] = f2bf(v);
}

// ---------------------------------------------------------------------------
// Fused GEMM. Per wg (mt,nt,b): rows mt*128..+128, cols nt*128..+128 of block
// b. 256 threads = 4 waves (2x2), wave tile 64x64, 4x4 frags 16x16x32 bf16.
// LDS tiles XOR-swizzled: physical 16B chunk = logical ^ (row&7); for
// global_load_lds the swizzle is applied via the per-lane SOURCE address.
// Grid 512 = 32(mt) * 4(b) * 4(nt), nt fastest (x-row reuse locality).
// ---------------------------------------------------------------------------
__global__ __launch_bounds__(256, 3) void gemm_k(
    const float* __restrict__ x, const int* __restrict__ mask,
    const float* __restrict__ mean, const float* __restrict__ bias,
    const unsigned short* __restrict__ Wp, const unsigned short* __restrict__ T,
    float* __restrict__ out) {
    __shared__ unsigned short Asm_[128 * 64];   // 16 KB, swizzled [row][k]
    __shared__ unsigned short Bsm_[128 * 64];   // 16 KB, swizzled [n][k]

    int bid = blockIdx.x;
    int nt  = bid & 3;
    int b   = (bid >> 2) & 3;
    int mt  = bid >> 4;
    int tid  = threadIdx.x;
    int lane = tid & 63;
    int w    = tid >> 6;
    int wm   = w >> 1;          // 0..1 -> rows 64*wm
    int wn   = w & 1;           // 0..1 -> cols 64*wn
    int quad = lane >> 4;
    int l16  = lane & 15;
    int row0 = mt * 128;
    int n0   = nt * 128;

    floatx4 acc[4][4];
#pragma unroll
    for (int m = 0; m < 4; ++m)
#pragma unroll
        for (int n = 0; n < 4; ++n) acc[m][n] = (floatx4){0.f, 0.f, 0.f, 0.f};

    for (int kt = 0; kt < NKT; ++kt) {
        // ---- stage A ----
        if (kt < 63) {
            // x path: mask/center/convert in registers, swizzled LDS write
#pragma unroll
            for (int i = 0; i < 4; ++i) {
                int c  = i * 256 + tid;
                int r  = c >> 3;        // row 0..127
                int cg = c & 7;         // logical (global) 16B chunk
                int col = kt * 64 + cg * 8;
                short8 v8 = (short8){0, 0, 0, 0, 0, 0, 0, 0};
                if (col < DIN) {        // col % 8 == 0 and DIN % 8 == 0
                    size_t gi = (size_t)(row0 + r) * XC + (size_t)b * DIN + col;
                    const float4* xp = reinterpret_cast<const float4*>(x + gi);
                    const int4*   mp = reinterpret_cast<const int4*>(mask + gi);
                    const float4* ep = reinterpret_cast<const float4*>(mean + b * DIN + col);
                    float4 x0 = xp[0], x1 = xp[1];
                    int4   m0 = mp[0], m1 = mp[1];
                    float4 e0 = ep[0], e1 = ep[1];
                    float f0 = m0.x ? x0.x - e0.x : 0.f;
                    float f1 = m0.y ? x0.y - e0.y : 0.f;
                    float f2 = m0.z ? x0.z - e0.z : 0.f;
                    float f3 = m0.w ? x0.w - e0.w : 0.f;
                    float f4 = m1.x ? x1.x - e1.x : 0.f;
                    float f5 = m1.y ? x1.y - e1.y : 0.f;
                    float f6 = m1.z ? x1.z - e1.z : 0.f;
                    float f7 = m1.w ? x1.w - e1.w : 0.f;
                    v8 = (short8){(short)f2bf(f0), (short)f2bf(f1), (short)f2bf(f2),
                                  (short)f2bf(f3), (short)f2bf(f4), (short)f2bf(f5),
                                  (short)f2bf(f6), (short)f2bf(f7)};
                }
                *reinterpret_cast<short8*>(&Asm_[r * 64 + ((cg ^ (r & 7)) * 8)]) = v8;
            }
        } else {
            // tail path: async copy from T, swizzle via source chunk select
#pragma unroll
            for (int i = 0; i < 4; ++i) {
                int c  = i * 256 + tid;
                int r  = c >> 3;
                int cl = c & 7;              // physical chunk (fixed by dest)
                int cg = cl ^ (r & 7);       // logical chunk to fetch
                const unsigned short* src =
                    T + ((size_t)(row0 + r) * NBLK + b) * TC + (kt - 63) * 64 + cg * 8;
                async16(src, &Asm_[c * 8]);
            }
        }
        // ---- stage B (async, swizzle via source chunk select) ----
#pragma unroll
        for (int i = 0; i < 4; ++i) {
            int c  = i * 256 + tid;
            int nl = c >> 3;
            int cl = c & 7;
            int cg = cl ^ (nl & 7);
            const unsigned short* src =
                Wp + ((size_t)(b * DLAT + n0 + nl)) * KPAD + kt * 64 + cg * 8;
            async16(src, &Bsm_[c * 8]);
        }
        __syncthreads();
        // ---- MFMA ----
#pragma unroll
        for (int s = 0; s < 2; ++s) {
            short8 af[4], bfr[4];
#pragma unroll
            for (int m = 0; m < 4; ++m) {
                int ar = wm * 64 + m * 16 + l16;
                af[m] = *reinterpret_cast<const short8*>(
                    &Asm_[ar * 64 + (((s * 4 + quad) ^ (ar & 7)) * 8)]);
            }
#pragma unroll
            for (int n = 0; n < 4; ++n) {
                int br = wn * 64 + n * 16 + l16;
                bfr[n] = *reinterpret_cast<const short8*>(
                    &Bsm_[br * 64 + (((s * 4 + quad) ^ (br & 7)) * 8)]);
            }
#pragma unroll
            for (int m = 0; m < 4; ++m)
#pragma unroll
                for (int n = 0; n < 4; ++n)
                    acc[m][n] = __builtin_amdgcn_mfma_f32_16x16x32_bf16(
                        af[m], bfr[n], acc[m][n], 0, 0, 0);
        }
        __syncthreads();
    }

    // ---- epilogue: bias + LeakyReLU(0.3) ----
#pragma unroll
    for (int m = 0; m < 4; ++m) {
#pragma unroll
        for (int n = 0; n < 4; ++n) {
            int col_l = wn * 64 + n * 16 + l16;
            float bv = bias[b * DLAT + n0 + col_l];
#pragma unroll
            for (int r = 0; r < 4; ++r) {
                int row_l = wm * 64 + m * 16 + quad * 4 + r;
                float v = acc[m][n][r] + bv;
                v = v >= 0.f ? v : 0.3f * v;
                out[(size_t)(row0 + row_l) * OUTC + b * DLAT + n0 + col_l] = v;
            }
        }
    }
}

extern "C" void kernel_launch(void* const* d_in, const int* in_sizes, int n_in,
                              void* d_out, int out_size, void* d_ws, size_t ws_size,
                              hipStream_t stream) {
    const float* x       = (const float*)d_in[0];
    const int*   mask    = (const int*)d_in[1];
    const float* embed   = (const float*)d_in[2];
    const float* batches = (const float*)d_in[3];
    const float* mean    = (const float*)d_in[4];
    const float* W       = (const float*)d_in[5];
    const float* bias    = (const float*)d_in[6];
    float* out = (float*)d_out;

    unsigned short* Wp = (unsigned short*)d_ws;                 // 4*512*4224 bf16 = 17.3 MB
    unsigned short* T  = Wp + (size_t)NBLK * DLAT * KPAD;       // 4096*4*192 bf16 = 6.3 MB

    prep_w<<<dim3(2112), dim3(256), 0, stream>>>(W, Wp);
    prep_t<<<dim3(12288), dim3(256), 0, stream>>>(embed, batches, T);
    gemm_k<<<dim3(512), dim3(256), 0, stream>>>(x, mask, mean, bias, Wp, T, out);
}

// Round 4
// 654.064 us; speedup vs baseline: 1.1461x; 1.1461x over previous
//
#include <hip/hip_runtime.h>

#define NROWS 4096
#define NBLK 4
#define DIN 4000
#define DE 128
#define DB 8
#define DLAT 512
#define FANIN 4136
#define KPAD 4224   // 66 * 64
#define NKT 66
#define XC 16000    // NBLK*DIN
#define OUTC 2048   // NBLK*DLAT
#define TC 192      // fallback tail columns: 128 embed + 8 batch + 56 pad

typedef __attribute__((ext_vector_type(8))) short short8;
typedef __attribute__((ext_vector_type(4))) float floatx4;

__device__ __forceinline__ unsigned short f2bf(float f) {
    unsigned int u = __builtin_bit_cast(unsigned int, f);
    u = (u + 0x7FFFu + ((u >> 16) & 1u)) >> 16;
    return (unsigned short)u;
}

__device__ __forceinline__ void async16(const void* g, void* l) {
    __builtin_amdgcn_global_load_lds(
        (const __attribute__((address_space(1))) void*)g,
        (__attribute__((address_space(3))) void*)l, 16, 0, 0);
}

// ---------------------------------------------------------------------------
// Pack W (fp32 [4][4136][512]) -> Wp (bf16 [4][512][4224], n-major, K padded).
// packed k: [0,4000)=x rows, [4000,4032)=0, [4032,4160)=embed rows,
// [4160,4168)=batch rows, [4168,4224)=0. LDS-transpose: reads+writes coalesced.
// ---------------------------------------------------------------------------
__global__ void prep_w(const float* __restrict__ W, unsigned short* __restrict__ Wp) {
    __shared__ unsigned short tile[64 * 68];   // [k 64][n 64], stride 68
    int bid = blockIdx.x;
    int nt = bid & 7;
    int t2 = bid >> 3;
    int kt = t2 % 66;
    int b  = t2 / 66;
    int tid = threadIdx.x;
    int n0 = nt * 64;
    int k0 = kt * 64;
#pragma unroll
    for (int i = 0; i < 4; ++i) {
        int c = i * 256 + tid;
        int r = c >> 4;             // k-row in tile
        int q = (c & 15) * 4;       // n-col
        int pk = k0 + r;
        int wr = (pk < DIN) ? pk : ((pk >= 4032 && pk < 4168) ? pk - 32 : -1);
        float4 v = make_float4(0.f, 0.f, 0.f, 0.f);
        if (wr >= 0)
            v = *reinterpret_cast<const float4*>(W + ((size_t)b * FANIN + wr) * DLAT + n0 + q);
        ushort4 u4 = make_ushort4(f2bf(v.x), f2bf(v.y), f2bf(v.z), f2bf(v.w));
        *reinterpret_cast<ushort4*>(&tile[r * 68 + q]) = u4;
    }
    __syncthreads();
#pragma unroll
    for (int i = 0; i < 2; ++i) {
        int c = i * 256 + tid;
        int nl = c >> 3;            // n within tile
        int kc = c & 7;             // 16B k-chunk
        unsigned short o[8];
#pragma unroll
        for (int j = 0; j < 8; ++j) o[j] = tile[(kc * 8 + j) * 68 + nl];
        *reinterpret_cast<short8*>(Wp + ((size_t)(b * DLAT + n0 + nl)) * KPAD + k0 + kc * 8) =
            *reinterpret_cast<const short8*>(o);
    }
}

// ---------------------------------------------------------------------------
// FAST PATH: pre-process A once. Xp bf16 [4096][4][4224]:
// k [0,4000) = mask ? x - mean : 0 ; [4000,4032)=0 ; [4032,4160)=embed ;
// [4160,4168)=batches ; [4168,4224)=0.  Pure stream: 524 MB in, 138 MB out.
// ---------------------------------------------------------------------------
__global__ void prep_x(const float* __restrict__ x, const int* __restrict__ mask,
                       const float* __restrict__ mean, const float* __restrict__ embed,
                       const float* __restrict__ batches, unsigned short* __restrict__ Xp) {
    int c = blockIdx.x * 256 + threadIdx.x;   // over 4096*4*528 = 8,650,752
    int chunk = c % 528;
    int rb    = c / 528;      // row*4 + b
    int b   = rb & 3;
    int row = rb >> 2;
    int k   = chunk * 8;
    short8 v8 = (short8){0, 0, 0, 0, 0, 0, 0, 0};
    if (k < DIN) {
        size_t gi = (size_t)row * XC + b * DIN + k;
        const float4* xp = reinterpret_cast<const float4*>(x + gi);
        const int4*   mp = reinterpret_cast<const int4*>(mask + gi);
        const float4* ep = reinterpret_cast<const float4*>(mean + b * DIN + k);
        float4 x0 = xp[0], x1 = xp[1];
        int4   m0 = mp[0], m1 = mp[1];
        float4 e0 = ep[0], e1 = ep[1];
        float f0 = m0.x ? x0.x - e0.x : 0.f;
        float f1 = m0.y ? x0.y - e0.y : 0.f;
        float f2 = m0.z ? x0.z - e0.z : 0.f;
        float f3 = m0.w ? x0.w - e0.w : 0.f;
        float f4 = m1.x ? x1.x - e1.x : 0.f;
        float f5 = m1.y ? x1.y - e1.y : 0.f;
        float f6 = m1.z ? x1.z - e1.z : 0.f;
        float f7 = m1.w ? x1.w - e1.w : 0.f;
        v8 = (short8){(short)f2bf(f0), (short)f2bf(f1), (short)f2bf(f2), (short)f2bf(f3),
                      (short)f2bf(f4), (short)f2bf(f5), (short)f2bf(f6), (short)f2bf(f7)};
    } else if (k >= 4032 && k < 4160) {
        const float4* ep = reinterpret_cast<const float4*>(
            embed + (size_t)row * (NBLK * DE) + b * DE + (k - 4032));
        float4 a = ep[0], bb = ep[1];
        v8 = (short8){(short)f2bf(a.x), (short)f2bf(a.y), (short)f2bf(a.z), (short)f2bf(a.w),
                      (short)f2bf(bb.x), (short)f2bf(bb.y), (short)f2bf(bb.z), (short)f2bf(bb.w)};
    } else if (k == 4160) {
        const float4* bp = reinterpret_cast<const float4*>(batches + (size_t)row * DB);
        float4 a = bp[0], bb = bp[1];
        v8 = (short8){(short)f2bf(a.x), (short)f2bf(a.y), (short)f2bf(a.z), (short)f2bf(a.w),
                      (short)f2bf(bb.x), (short)f2bf(bb.y), (short)f2bf(bb.z), (short)f2bf(bb.w)};
    }
    *reinterpret_cast<short8*>(Xp + (size_t)rb * KPAD + k) = v8;
}

// ---------------------------------------------------------------------------
// FAST GEMM (m97 structure): both operands via global_load_lds width-16 into
// XOR-swizzled LDS (physical chunk = logical ^ (row&7), applied on SOURCE
// address so the wave-uniform LDS dest constraint holds). 256 thr = 4 waves
// (2x2), wave tile 64x64, 4x4 frags of 16x16x32 bf16. Grid 512.
// ---------------------------------------------------------------------------
__global__ __launch_bounds__(256, 3) void gemm_x(
    const float* __restrict__ bias, const unsigned short* __restrict__ Wp,
    const unsigned short* __restrict__ Xp, float* __restrict__ out) {
    __shared__ unsigned short Asm_[128 * 64];
    __shared__ unsigned short Bsm_[128 * 64];

    int bid = blockIdx.x;
    int nt  = bid & 3;
    int b   = (bid >> 2) & 3;
    int mt  = bid >> 4;
    int tid  = threadIdx.x;
    int lane = tid & 63;
    int w    = tid >> 6;
    int wm   = w >> 1;
    int wn   = w & 1;
    int quad = lane >> 4;
    int l16  = lane & 15;
    int row0 = mt * 128;
    int n0   = nt * 128;

    floatx4 acc[4][4];
#pragma unroll
    for (int m = 0; m < 4; ++m)
#pragma unroll
        for (int n = 0; n < 4; ++n) acc[m][n] = (floatx4){0.f, 0.f, 0.f, 0.f};

    const unsigned short* Abase = Xp + ((size_t)row0 * NBLK + b) * KPAD;
    const unsigned short* Bbase = Wp + ((size_t)(b * DLAT + n0)) * KPAD;

    for (int kt = 0; kt < NKT; ++kt) {
        int k0 = kt * 64;
        // ---- stage A ----
#pragma unroll
        for (int i = 0; i < 4; ++i) {
            int c  = i * 256 + tid;
            int r  = c >> 3;
            int cg = (c & 7) ^ (r & 7);
            async16(Abase + (size_t)r * (NBLK * KPAD) + k0 + cg * 8, &Asm_[c * 8]);
        }
        // ---- stage B ----
#pragma unroll
        for (int i = 0; i < 4; ++i) {
            int c  = i * 256 + tid;
            int nl = c >> 3;
            int cg = (c & 7) ^ (nl & 7);
            async16(Bbase + (size_t)nl * KPAD + k0 + cg * 8, &Bsm_[c * 8]);
        }
        __syncthreads();
        // ---- MFMA ----
#pragma unroll
        for (int s = 0; s < 2; ++s) {
            short8 af[4], bfr[4];
#pragma unroll
            for (int m = 0; m < 4; ++m) {
                int ar = wm * 64 + m * 16 + l16;
                af[m] = *reinterpret_cast<const short8*>(
                    &Asm_[ar * 64 + (((s * 4 + quad) ^ (ar & 7)) * 8)]);
            }
#pragma unroll
            for (int n = 0; n < 4; ++n) {
                int br = wn * 64 + n * 16 + l16;
                bfr[n] = *reinterpret_cast<const short8*>(
                    &Bsm_[br * 64 + (((s * 4 + quad) ^ (br & 7)) * 8)]);
            }
#pragma unroll
            for (int m = 0; m < 4; ++m)
#pragma unroll
                for (int n = 0; n < 4; ++n)
                    acc[m][n] = __builtin_amdgcn_mfma_f32_16x16x32_bf16(
                        af[m], bfr[n], acc[m][n], 0, 0, 0);
        }
        __syncthreads();
    }

#pragma unroll
    for (int m = 0; m < 4; ++m) {
#pragma unroll
        for (int n = 0; n < 4; ++n) {
            int col_l = wn * 64 + n * 16 + l16;
            float bv = bias[b * DLAT + n0 + col_l];
#pragma unroll
            for (int r = 0; r < 4; ++r) {
                int row_l = wm * 64 + m * 16 + quad * 4 + r;
                float v = acc[m][n][r] + bv;
                v = v >= 0.f ? v : 0.3f * v;
                out[(size_t)(row0 + row_l) * OUTC + b * DLAT + n0 + col_l] = v;
            }
        }
    }
}

// ---------------------------------------------------------------------------
// FALLBACK (ws too small for Xp): round-3 kernels, verified passing.
// ---------------------------------------------------------------------------
__global__ void prep_t(const float* __restrict__ embed, const float* __restrict__ batches,
                       unsigned short* __restrict__ T) {
    int i  = blockIdx.x * 256 + threadIdx.x;
    int t  = i % TC;
    int nb = i / TC;
    int b  = nb & 3;
    int n  = nb >> 2;
    float v = 0.f;
    if (t < DE)            v = embed[(size_t)n * (NBLK * DE) + b * DE + t];
    else if (t < DE + DB)  v = batches[(size_t)n * DB + (t - DE)];
    T[i] = f2bf(v);
}

__global__ __launch_bounds__(256, 3) void gemm_k(
    const float* __restrict__ x, const int* __restrict__ mask,
    const float* __restrict__ mean, const float* __restrict__ bias,
    const unsigned short* __restrict__ Wp, const unsigned short* __restrict__ T,
    float* __restrict__ out) {
    __shared__ unsigned short Asm_[128 * 64];
    __shared__ unsigned short Bsm_[128 * 64];

    int bid = blockIdx.x;
    int nt  = bid & 3;
    int b   = (bid >> 2) & 3;
    int mt  = bid >> 4;
    int tid  = threadIdx.x;
    int lane = tid & 63;
    int w    = tid >> 6;
    int wm   = w >> 1;
    int wn   = w & 1;
    int quad = lane >> 4;
    int l16  = lane & 15;
    int row0 = mt * 128;
    int n0   = nt * 128;

    floatx4 acc[4][4];
#pragma unroll
    for (int m = 0; m < 4; ++m)
#pragma unroll
        for (int n = 0; n < 4; ++n) acc[m][n] = (floatx4){0.f, 0.f, 0.f, 0.f};

    for (int kt = 0; kt < NKT; ++kt) {
        if (kt < 63) {
#pragma unroll
            for (int i = 0; i < 4; ++i) {
                int c  = i * 256 + tid;
                int r  = c >> 3;
                int cg = c & 7;
                int col = kt * 64 + cg * 8;
                short8 v8 = (short8){0, 0, 0, 0, 0, 0, 0, 0};
                if (col < DIN) {
                    size_t gi = (size_t)(row0 + r) * XC + (size_t)b * DIN + col;
                    const float4* xp = reinterpret_cast<const float4*>(x + gi);
                    const int4*   mp = reinterpret_cast<const int4*>(mask + gi);
                    const float4* ep = reinterpret_cast<const float4*>(mean + b * DIN + col);
                    float4 x0 = xp[0], x1 = xp[1];
                    int4   m0 = mp[0], m1 = mp[1];
                    float4 e0 = ep[0], e1 = ep[1];
                    float f0 = m0.x ? x0.x - e0.x : 0.f;
                    float f1 = m0.y ? x0.y - e0.y : 0.f;
                    float f2 = m0.z ? x0.z - e0.z : 0.f;
                    float f3 = m0.w ? x0.w - e0.w : 0.f;
                    float f4 = m1.x ? x1.x - e1.x : 0.f;
                    float f5 = m1.y ? x1.y - e1.y : 0.f;
                    float f6 = m1.z ? x1.z - e1.z : 0.f;
                    float f7 = m1.w ? x1.w - e1.w : 0.f;
                    v8 = (short8){(short)f2bf(f0), (short)f2bf(f1), (short)f2bf(f2),
                                  (short)f2bf(f3), (short)f2bf(f4), (short)f2bf(f5),
                                  (short)f2bf(f6), (short)f2bf(f7)};
                }
                *reinterpret_cast<short8*>(&Asm_[r * 64 + ((cg ^ (r & 7)) * 8)]) = v8;
            }
        } else {
#pragma unroll
            for (int i = 0; i < 4; ++i) {
                int c  = i * 256 + tid;
                int r  = c >> 3;
                int cg = (c & 7) ^ (r & 7);
                async16(T + ((size_t)(row0 + r) * NBLK + b) * TC + (kt - 63) * 64 + cg * 8,
                        &Asm_[c * 8]);
            }
        }
#pragma unroll
        for (int i = 0; i < 4; ++i) {
            int c  = i * 256 + tid;
            int nl = c >> 3;
            int cg = (c & 7) ^ (nl & 7);
            async16(Wp + ((size_t)(b * DLAT + n0 + nl)) * KPAD + kt * 64 + cg * 8,
                    &Bsm_[c * 8]);
        }
        __syncthreads();
#pragma unroll
        for (int s = 0; s < 2; ++s) {
            short8 af[4], bfr[4];
#pragma unroll
            for (int m = 0; m < 4; ++m) {
                int ar = wm * 64 + m * 16 + l16;
                af[m] = *reinterpret_cast<const short8*>(
                    &Asm_[ar * 64 + (((s * 4 + quad) ^ (ar & 7)) * 8)]);
            }
#pragma unroll
            for (int n = 0; n < 4; ++n) {
                int br = wn * 64 + n * 16 + l16;
                bfr[n] = *reinterpret_cast<const short8*>(
                    &Bsm_[br * 64 + (((s * 4 + quad) ^ (br & 7)) * 8)]);
            }
#pragma unroll
            for (int m = 0; m < 4; ++m)
#pragma unroll
                for (int n = 0; n < 4; ++n)
                    acc[m][n] = __builtin_amdgcn_mfma_f32_16x16x32_bf16(
                        af[m], bfr[n], acc[m][n], 0, 0, 0);
        }
        __syncthreads();
    }

#pragma unroll
    for (int m = 0; m < 4; ++m) {
#pragma unroll
        for (int n = 0; n < 4; ++n) {
            int col_l = wn * 64 + n * 16 + l16;
            float bv = bias[b * DLAT + n0 + col_l];
#pragma unroll
            for (int r = 0; r < 4; ++r) {
                int row_l = wm * 64 + m * 16 + quad * 4 + r;
                float v = acc[m][n][r] + bv;
                v = v >= 0.f ? v : 0.3f * v;
                out[(size_t)(row0 + row_l) * OUTC + b * DLAT + n0 + col_l] = v;
            }
        }
    }
}

extern "C" void kernel_launch(void* const* d_in, const int* in_sizes, int n_in,
                              void* d_out, int out_size, void* d_ws, size_t ws_size,
                              hipStream_t stream) {
    const float* x       = (const float*)d_in[0];
    const int*   mask    = (const int*)d_in[1];
    const float* embed   = (const float*)d_in[2];
    const float* batches = (const float*)d_in[3];
    const float* mean    = (const float*)d_in[4];
    const float* W       = (const float*)d_in[5];
    const float* bias    = (const float*)d_in[6];
    float* out = (float*)d_out;

    unsigned short* Wp = (unsigned short*)d_ws;                 // 17.3 MB
    size_t wp_elems = (size_t)NBLK * DLAT * KPAD;               // 8,650,752
    size_t xp_elems = (size_t)NROWS * NBLK * KPAD;              // 69,206,016
    size_t need_fast = (wp_elems + xp_elems) * 2;               // 155,713,536 B

    prep_w<<<dim3(2112), dim3(256), 0, stream>>>(W, Wp);

    if (ws_size >= need_fast) {
        unsigned short* Xp = Wp + wp_elems;                     // 138.4 MB
        prep_x<<<dim3(33792), dim3(256), 0, stream>>>(x, mask, mean, embed, batches, Xp);
        gemm_x<<<dim3(512), dim3(256), 0, stream>>>(bias, Wp, Xp, out);
    } else {
        unsigned short* T = Wp + wp_elems;                      // 6.3 MB
        prep_t<<<dim3(12288), dim3(256), 0, stream>>>(embed, batches, T);
        gemm_k<<<dim3(512), dim3(256), 0, stream>>>(x, mask, mean, bias, Wp, T, out);
    }
}